// Round 11
// baseline (554.001 us; speedup 1.0000x reference)
//
#include <hip/hip_runtime.h>
#include <hip/hip_bf16.h>
#include <math.h>

#define T_ 128
#define NE_ 64
#define NA_ 8
#define B_ 512
#define OBS_ 64
#define D_ 128
#define CH_ 128
#define VH_ 256
#define M_ (T_*B_)   // 65536

typedef __attribute__((ext_vector_type(8))) short bf16x8;
typedef __attribute__((ext_vector_type(4))) float f32x4;
typedef __attribute__((ext_vector_type(4))) unsigned short u16x4;

__device__ __forceinline__ float sigmoidf_(float x){ return 1.f/(1.f+__expf(-x)); }
__device__ __forceinline__ unsigned short f2bu(float v){
  __hip_bfloat16 b = __float2bfloat16(v);
  return __builtin_bit_cast(unsigned short, b);
}
__device__ __forceinline__ float bu2f(unsigned short u){
  return __builtin_bit_cast(float, (unsigned int)u << 16);
}
__device__ __forceinline__ float ulo(unsigned int u){ return __builtin_bit_cast(float, u << 16); }
__device__ __forceinline__ float uhi(unsigned int u){ return __builtin_bit_cast(float, u & 0xFFFF0000u); }

// ---------------------------------------------------------------------------
// Split-precision MFMA GEMM (fp32-class): C = epi(A @ B + bias)
// A = (Ah,Al) bf16 [M][K]; B = (BTh,BTl) bf16 [N][K]. acc = AhBh + AhBl + AlBh.
// ---------------------------------------------------------------------------
template<int ACT, bool WF32, bool WSPLIT>
__global__ __launch_bounds__(256)
void mgemm3_k(const __hip_bfloat16* __restrict__ Ah, const __hip_bfloat16* __restrict__ Al,
              const __hip_bfloat16* __restrict__ BTh, const __hip_bfloat16* __restrict__ BTl,
              const float* __restrict__ bias, float* __restrict__ C,
              __hip_bfloat16* __restrict__ Ch, __hip_bfloat16* __restrict__ Cl,
              int M, int N, int K)
{
  __shared__ ushort Ash[128*72], Asl[128*72];
  __shared__ ushort Bsh[64*72],  Bsl[64*72];
  const int tid  = threadIdx.x;
  const int lane = tid & 63, wave = tid >> 6;
  const int wm = wave >> 1, wn = wave & 1;
  const int quad = lane >> 4, ln = lane & 15;
  const int n0 = blockIdx.x * 64;
  const int m0 = blockIdx.y * 128;

  f32x4 acc[4][2];
  #pragma unroll
  for (int i=0;i<4;i++)
    #pragma unroll
    for (int j=0;j<2;j++)
      #pragma unroll
      for (int r=0;r<4;r++) acc[i][j][r] = 0.f;

  for (int kc=0; kc<K; kc+=64){
    #pragma unroll
    for (int i=0;i<4;i++){
      int c8 = tid + i*256;
      int m = c8 >> 3, kq = (c8 & 7)*8;
      *(uint4*)&Ash[m*72+kq] = *(const uint4*)&Ah[(size_t)(m0+m)*K + kc + kq];
      *(uint4*)&Asl[m*72+kq] = *(const uint4*)&Al[(size_t)(m0+m)*K + kc + kq];
    }
    #pragma unroll
    for (int i=0;i<2;i++){
      int c8 = tid + i*256;
      int n = c8 >> 3, kq = (c8 & 7)*8;
      *(uint4*)&Bsh[n*72+kq] = *(const uint4*)&BTh[(size_t)(n0+n)*K + kc + kq];
      *(uint4*)&Bsl[n*72+kq] = *(const uint4*)&BTl[(size_t)(n0+n)*K + kc + kq];
    }
    __syncthreads();
    #pragma unroll
    for (int ks=0; ks<2; ks++){
      const int kq = ks*32 + quad*8;
      bf16x8 ah[4], al[4], bh[2], bl[2];
      #pragma unroll
      for (int mt=0;mt<4;mt++){
        ah[mt] = *(const bf16x8*)&Ash[(wm*64 + mt*16 + ln)*72 + kq];
        al[mt] = *(const bf16x8*)&Asl[(wm*64 + mt*16 + ln)*72 + kq];
      }
      #pragma unroll
      for (int nt=0;nt<2;nt++){
        bh[nt] = *(const bf16x8*)&Bsh[(wn*32 + nt*16 + ln)*72 + kq];
        bl[nt] = *(const bf16x8*)&Bsl[(wn*32 + nt*16 + ln)*72 + kq];
      }
      #pragma unroll
      for (int mt=0;mt<4;mt++)
        #pragma unroll
        for (int nt=0;nt<2;nt++){
          acc[mt][nt] = __builtin_amdgcn_mfma_f32_16x16x32_bf16(ah[mt], bh[nt], acc[mt][nt], 0,0,0);
          acc[mt][nt] = __builtin_amdgcn_mfma_f32_16x16x32_bf16(ah[mt], bl[nt], acc[mt][nt], 0,0,0);
          acc[mt][nt] = __builtin_amdgcn_mfma_f32_16x16x32_bf16(al[mt], bh[nt], acc[mt][nt], 0,0,0);
        }
    }
    __syncthreads();
  }

  float biasv[2];
  #pragma unroll
  for (int nt=0;nt<2;nt++) biasv[nt] = bias ? bias[n0 + wn*32 + nt*16 + ln] : 0.f;
  #pragma unroll
  for (int mt=0;mt<4;mt++){
    #pragma unroll
    for (int r=0;r<4;r++){
      int row = m0 + wm*64 + mt*16 + quad*4 + r;
      #pragma unroll
      for (int nt=0;nt<2;nt++){
        int col = n0 + wn*32 + nt*16 + ln;
        float v = acc[mt][nt][r] + biasv[nt];
        if (ACT==1) v = fmaxf(v, 0.f);
        if (WF32) C[(size_t)row*N + col] = v;
        if (WSPLIT){
          __hip_bfloat16 h = __float2bfloat16(v);
          Ch[(size_t)row*N + col] = h;
          Cl[(size_t)row*N + col] = __float2bfloat16(v - __bfloat162float(h));
        }
      }
    }
  }
}

// ---------------------------------------------------------------------------
// bf16 MFMA GEMM (post-GRU): BT = B^T [N,K] bf16; 128x128 tile, BK=128.
// RESID: += bf16 resid AFTER act.  SCALE: *= alive.  Write bf16.
// ---------------------------------------------------------------------------
template<int ACT, bool DUAL, bool RESID, bool SCALE>
__global__ __launch_bounds__(256)
void mgemm_k(const __hip_bfloat16* __restrict__ A, const __hip_bfloat16* __restrict__ A2,
             const __hip_bfloat16* __restrict__ BT, const float* __restrict__ bias,
             const unsigned short* __restrict__ resid, const int* __restrict__ dones,
             __hip_bfloat16* __restrict__ Cb, int M, int N, int K)
{
  __shared__ ushort As[128*136];
  __shared__ ushort Bs[128*136];
  const int tid  = threadIdx.x;
  const int lane = tid & 63, wave = tid >> 6;
  const int wm = wave >> 1, wn = wave & 1;
  const int quad = lane >> 4, ln = lane & 15;
  const int n0 = blockIdx.x * 128;
  const int m0 = blockIdx.y * 128;

  f32x4 acc[4][4];
  #pragma unroll
  for (int i=0;i<4;i++)
    #pragma unroll
    for (int j=0;j<4;j++)
      #pragma unroll
      for (int r=0;r<4;r++) acc[i][j][r] = 0.f;

  for (int kc=0; kc<K; kc+=128){
    const __hip_bfloat16* Ab; int arow, akoff;
    if (DUAL) { Ab = kc ? A2 : A; arow = 128; akoff = 0; }
    else      { Ab = A;           arow = K;   akoff = kc; }
    #pragma unroll
    for (int i=0;i<8;i++){
      int c8 = tid + i*256;
      int m = c8 >> 4, kq = (c8 & 15)*8;
      *(uint4*)&As[m*136 + kq] = *(const uint4*)&Ab[(size_t)(m0+m)*arow + akoff + kq];
    }
    #pragma unroll
    for (int i=0;i<8;i++){
      int c8 = tid + i*256;
      int n = c8 >> 4, kq = (c8 & 15)*8;
      *(uint4*)&Bs[n*136 + kq] = *(const uint4*)&BT[(size_t)(n0+n)*K + kc + kq];
    }
    __syncthreads();
    #pragma unroll
    for (int ks=0; ks<4; ks++){
      const int kq = ks*32 + quad*8;
      bf16x8 af[4], bfv[4];
      #pragma unroll
      for (int mt=0;mt<4;mt++)
        af[mt] = *(const bf16x8*)&As[(wm*64 + mt*16 + ln)*136 + kq];
      #pragma unroll
      for (int nt=0;nt<4;nt++)
        bfv[nt] = *(const bf16x8*)&Bs[(wn*64 + nt*16 + ln)*136 + kq];
      #pragma unroll
      for (int mt=0;mt<4;mt++)
        #pragma unroll
        for (int nt=0;nt<4;nt++)
          acc[mt][nt] = __builtin_amdgcn_mfma_f32_16x16x32_bf16(af[mt], bfv[nt], acc[mt][nt], 0,0,0);
    }
    __syncthreads();
  }

  float biasv[4];
  #pragma unroll
  for (int nt=0;nt<4;nt++){
    int col = n0 + wn*64 + nt*16 + ln;
    biasv[nt] = bias ? bias[col] : 0.f;
  }
  #pragma unroll
  for (int mt=0;mt<4;mt++){
    #pragma unroll
    for (int r=0;r<4;r++){
      int row = m0 + wm*64 + mt*16 + quad*4 + r;
      float al = 1.f;
      if (SCALE) al = (dones[row]!=0) ? 0.f : 1.f;
      #pragma unroll
      for (int nt=0;nt<4;nt++){
        int col = n0 + wn*64 + nt*16 + ln;
        float v = acc[mt][nt][r] + biasv[nt];
        if (ACT==1) v = fmaxf(v, 0.f);
        if (RESID)  v += bu2f(resid[(size_t)row*N + col]);
        if (SCALE)  v *= al;
        Cb[(size_t)row*N + col] = __float2bfloat16(v);
      }
    }
  }
}

// ---------------------------------------------------------------------------
// MFMA GRU v7. Round-10 analysis: step was LDS-BW-bound — every wave read
// full 16-row A-frags (64KB/block/step) for only 4 real rows. Fix: MFMA rows
// are independent (D[m]=A[m]·B), so fake-row lanes read the SAME address as
// their quad's real row (ln&12) -> LDS same-address broadcast, traffic /4.
// Fake C-rows contain bounded garbage; only reg 0 (rows 4q) is consumed.
// Also: e-store deferred to after the barrier (pre-barrier vmcnt(0) no
// longer drains a hot store), and gate MFMA chains split 12->2x6 deep.
// 1 barrier/step, h double-buffered, reset-carry semantics (round-6 fix).
// ---------------------------------------------------------------------------
__global__ __launch_bounds__(512, 1)
void grum7_k(const float* __restrict__ giA, const float* __restrict__ giB,
             const float* __restrict__ hidden0,
             const int* __restrict__ dones, const float* __restrict__ gWh,
             const float* __restrict__ bhn, __hip_bfloat16* __restrict__ eb_out,
             float* __restrict__ hout)
{
  __shared__ ushort wstg[32*392];
  __shared__ ushort hhi[2][16*136], hlo[2][16*136];
  __shared__ float  dnS[T_*4];
  const int tid  = threadIdx.x;
  const int lane = tid & 63, wave = tid >> 6;   // 8 waves
  const int quad = lane >> 4, ln = lane & 15;
  const int r0   = blockIdx.x * 4;
  const int col  = wave*16 + ln;      // h-dim owned by this lane
  const int lnb  = ln & 12;           // broadcast A-row (real rows 0,4,8,12)

  dnS[tid] = (dones[(size_t)(tid>>2)*B_ + r0 + (tid&3)] != 0) ? 1.f : 0.f;
  const float bhnr = bhn[col];

  for (int i=tid; i<16*136; i+=512){
    hhi[0][i]=0; hlo[0][i]=0; hhi[1][i]=0; hlo[1][i]=0;
  }

  // Wh hi/lo B-fragments in registers (cols g*128+col), staged via LDS
  bf16x8 bfh[3][4], bfl[3][4];
  #pragma unroll
  for (int kc=0; kc<4; kc++){    // hi pass
    for (int i=tid; i<32*384; i+=512){
      int kk = i/384, c = i - kk*384;
      wstg[kk*392 + c] = f2bu(gWh[(size_t)(kc*32+kk)*384 + c]);
    }
    __syncthreads();
    #pragma unroll
    for (int g=0; g<3; g++){
      int c = g*128 + col;
      #pragma unroll
      for (int j=0;j<8;j++)
        bfh[g][kc][j] = (short)wstg[(quad*8+j)*392 + c];
    }
    __syncthreads();
  }
  #pragma unroll
  for (int kc=0; kc<4; kc++){    // lo pass
    for (int i=tid; i<32*384; i+=512){
      int kk = i/384, c = i - kk*384;
      float v = gWh[(size_t)(kc*32+kk)*384 + c];
      wstg[kk*392 + c] = f2bu(v - bu2f(f2bu(v)));
    }
    __syncthreads();
    #pragma unroll
    for (int g=0; g<3; g++){
      int c = g*128 + col;
      #pragma unroll
      for (int j=0;j<8;j++)
        bfl[g][kc][j] = (short)wstg[(quad*8+j)*392 + c];
    }
    __syncthreads();
  }

  // init h: lane owns (row=quad, dim=col); batch row q lives at A/C-row 4q
  float hc = hidden0[(size_t)(r0+quad)*D_ + col];
  if (dnS[quad] > 0.5f) hc = 0.f;
  {
    ushort hh = f2bu(hc), hl = f2bu(hc - bu2f(hh));
    hhi[0][(quad*4)*136 + col] = hh;
    hlo[0][(quad*4)*136 + col] = hl;
  }
  __syncthreads();

  // prime gi[0]
  float c_r, c_z, c_n;
  {
    const float* gp = giA + ((size_t)(r0+quad))*384;
    c_r = gp[col]; c_z = gp[col+128]; c_n = gp[col+256];
  }

  ushort pend_eu = 0;   // deferred e-store (written after the barrier)

  for (int t=0; t<T_; t++){
    // deferred store of step t-1's e (post-barrier: drains free next barrier)
    if (t > 0)
      ((ushort*)eb_out)[((size_t)(t-1)*B_ + r0+quad)*D_ + col] = pend_eu;

    // distance-1 gi prefetch: consumed next step, drains at this barrier
    float n_r=0.f, n_z=0.f, n_n=0.f;
    if (t+1 < T_){
      const float* gp = (t+1 < 64) ? giA + ((size_t)(t+1)*B_ + r0+quad)*384
                                   : giB + ((size_t)(t+1-64)*B_ + r0+quad)*384;
      n_r = gp[col]; n_z = gp[col+128]; n_n = gp[col+256];
    }

    // MFMA phase: gh = h @ Wh (3-term split); broadcast A-reads (ln&12)
    const ushort* hbi = hhi[t&1];
    const ushort* hbl = hlo[t&1];
    f32x4 accA[3], accB[3];
    #pragma unroll
    for (int g=0;g<3;g++)
      #pragma unroll
      for (int r=0;r<4;r++){ accA[g][r]=0.f; accB[g][r]=0.f; }
    #pragma unroll
    for (int ks=0; ks<2; ks++){
      bf16x8 ahi = *(const bf16x8*)&hbi[lnb*136 + ks*32 + quad*8];
      bf16x8 alo = *(const bf16x8*)&hbl[lnb*136 + ks*32 + quad*8];
      #pragma unroll
      for (int g=0;g<3;g++){
        accA[g] = __builtin_amdgcn_mfma_f32_16x16x32_bf16(ahi, bfh[g][ks], accA[g], 0,0,0);
        accA[g] = __builtin_amdgcn_mfma_f32_16x16x32_bf16(alo, bfh[g][ks], accA[g], 0,0,0);
        accA[g] = __builtin_amdgcn_mfma_f32_16x16x32_bf16(ahi, bfl[g][ks], accA[g], 0,0,0);
      }
    }
    #pragma unroll
    for (int ks=2; ks<4; ks++){
      bf16x8 ahi = *(const bf16x8*)&hbi[lnb*136 + ks*32 + quad*8];
      bf16x8 alo = *(const bf16x8*)&hbl[lnb*136 + ks*32 + quad*8];
      #pragma unroll
      for (int g=0;g<3;g++){
        accB[g] = __builtin_amdgcn_mfma_f32_16x16x32_bf16(ahi, bfh[g][ks], accB[g], 0,0,0);
        accB[g] = __builtin_amdgcn_mfma_f32_16x16x32_bf16(alo, bfh[g][ks], accB[g], 0,0,0);
        accB[g] = __builtin_amdgcn_mfma_f32_16x16x32_bf16(ahi, bfl[g][ks], accB[g], 0,0,0);
      }
    }

    // gate phase: fully in-wave; lane (quad,ln) reg 0 = its (row,dim)
    const float dnow  = dnS[t*4 + quad];
    const float dnext = (t+1 < T_) ? dnS[(t+1)*4 + quad] : 0.f;
    float rg = sigmoidf_(c_r + accA[0][0] + accB[0][0]);
    float zg = sigmoidf_(c_z + accA[1][0] + accB[1][0]);
    float x  = c_n + rg*(accA[2][0] + accB[2][0] + bhnr);
    float ng = 2.f/(1.f+__expf(-2.f*x)) - 1.f;   // tanh
    float hnew = (1.f - zg)*ng + zg*hc;
    pend_eu = f2bu(hnew*(1.f-dnow));
    float hv = (dnext > 0.5f) ? 0.f : hnew;
    hc = hv;                               // carry the RESET h
    ushort hh = f2bu(hv), hl = f2bu(hv - bu2f(hh));
    hhi[(t+1)&1][(quad*4)*136 + col] = hh;
    hlo[(t+1)&1][(quad*4)*136 + col] = hl;
    __syncthreads();
    c_r = n_r; c_z = n_z; c_n = n_n;
  }
  ((ushort*)eb_out)[((size_t)(T_-1)*B_ + r0+quad)*D_ + col] = pend_eu;
  hout[(size_t)(r0+quad)*D_ + col] = hc;
}

// ---------------------------------------------------------------------------
// Coupling per (t,env), bf16 inputs: C_ij = sigmoid(relu(ai+aj+cb).w + cob),
// C_ii=0; ctx[i] = sum_j C_ij e[j] -> bf16.
// ---------------------------------------------------------------------------
__global__ __launch_bounds__(256)
void couple_k(const __hip_bfloat16* __restrict__ acat, const __hip_bfloat16* __restrict__ e,
              const float* __restrict__ chb, const float* __restrict__ cow,
              const float* __restrict__ cob, __hip_bfloat16* __restrict__ ctxb)
{
  __shared__ float ai[NA_][CH_], aj[NA_][CH_], es[NA_][D_], cbw[CH_], cww[CH_], Cs[NA_][NA_];
  const int m0 = blockIdx.x * NA_;
  const int tid = threadIdx.x;

  {
    int j = tid >> 5, q = (tid & 31)*8;
    uint4 u = *(const uint4*)((const ushort*)acat + (size_t)(m0+j)*256 + q);
    float f[8] = {ulo(u.x),uhi(u.x),ulo(u.y),uhi(u.y),ulo(u.z),uhi(u.z),ulo(u.w),uhi(u.w)};
    float* dst = (q < 128) ? &ai[j][q] : &aj[j][q-128];
    #pragma unroll
    for (int i=0;i<8;i++) dst[i] = f[i];
  }
  if (tid < 128){
    int j = tid >> 4, q = (tid & 15)*8;
    uint4 u = *(const uint4*)((const ushort*)e + (size_t)(m0+j)*D_ + q);
    float f[8] = {ulo(u.x),uhi(u.x),ulo(u.y),uhi(u.y),ulo(u.z),uhi(u.z),ulo(u.w),uhi(u.w)};
    #pragma unroll
    for (int i=0;i<8;i++) es[j][q+i] = f[i];
    cbw[tid] = chb[tid]; cww[tid] = cow[tid];
  }
  __syncthreads();

  {
    int p = tid >> 2, q = tid & 3;
    int i = p >> 3, j = p & 7;
    float s = 0.f;
    #pragma unroll
    for (int h = 0; h < 32; h++){
      int hh = q*32 + h;
      s += fmaxf(ai[i][hh] + aj[j][hh] + cbw[hh], 0.f) * cww[hh];
    }
    s += __shfl_down(s, 2);
    s += __shfl_down(s, 1);
    if (q == 0) {
      float Cv = sigmoidf_(s + cob[0]);
      Cs[i][j] = (i==j) ? 0.f : Cv;
    }
  }
  __syncthreads();
  #pragma unroll
  for (int rep=0; rep<4; rep++){
    int idx = rep*256 + tid;
    int i = idx >> 7, d = idx & 127;
    float s = 0.f;
    #pragma unroll
    for (int j=0;j<NA_;j++) s = fmaf(Cs[i][j], es[j][d], s);
    ctxb[(size_t)(m0+i)*D_ + d] = __float2bfloat16(s);
  }
}

// ---------------------------------------------------------------------------
// Fused preamble: all weight packs + obs split in ONE dispatch.
// ---------------------------------------------------------------------------
__global__ __launch_bounds__(256)
void packall_k(const float* __restrict__ obs, __hip_bfloat16* __restrict__ obsh, __hip_bfloat16* __restrict__ obsl,
               const float* __restrict__ e1w, __hip_bfloat16* __restrict__ e1h, __hip_bfloat16* __restrict__ e1l,
               const float* __restrict__ e2w, __hip_bfloat16* __restrict__ e2h, __hip_bfloat16* __restrict__ e2l,
               const float* __restrict__ gWi, __hip_bfloat16* __restrict__ gih, __hip_bfloat16* __restrict__ gil,
               const float* __restrict__ chw, __hip_bfloat16* __restrict__ bcatT,
               const float* __restrict__ uhw, __hip_bfloat16* __restrict__ uhwT,
               const float* __restrict__ uow, __hip_bfloat16* __restrict__ uowT,
               const float* __restrict__ v1w, __hip_bfloat16* __restrict__ v1wT,
               const float* __restrict__ v2w, __hip_bfloat16* __restrict__ v2wT)
{
  const int b = blockIdx.x, tid = threadIdx.x;
  if (b < 16384){
    int idx = b*256 + tid;
    float v = obs[idx];
    __hip_bfloat16 h = __float2bfloat16(v);
    obsh[idx] = h; obsl[idx] = __float2bfloat16(v - __bfloat162float(h));
  } else if (b < 16416){           // e1w [64][128] -> [n=128][k=64] hi/lo
    int idx = (b-16384)*256 + tid;
    int n = idx >> 6, k = idx & 63;
    float v = e1w[k*128 + n];
    __hip_bfloat16 h = __float2bfloat16(v);
    e1h[idx] = h; e1l[idx] = __float2bfloat16(v - __bfloat162float(h));
  } else if (b < 16480){           // e2w [128][128] -> [128][128] hi/lo
    int idx = (b-16416)*256 + tid;
    int n = idx >> 7, k = idx & 127;
    float v = e2w[k*128 + n];
    __hip_bfloat16 h = __float2bfloat16(v);
    e2h[idx] = h; e2l[idx] = __float2bfloat16(v - __bfloat162float(h));
  } else if (b < 16672){           // gWi [128][384] -> [384][128] hi/lo
    int idx = (b-16480)*256 + tid;
    int n = idx >> 7, k = idx & 127;
    float v = gWi[k*384 + n];
    __hip_bfloat16 h = __float2bfloat16(v);
    gih[idx] = h; gil[idx] = __float2bfloat16(v - __bfloat162float(h));
  } else if (b < 16800){           // bcatT [256][128]
    int idx = (b-16672)*256 + tid;
    int n = idx >> 7, k = idx & 127;
    float v = (n < 128) ? chw[k*128 + n] : chw[(128+k)*128 + (n-128)];
    bcatT[idx] = __float2bfloat16(v);
  } else if (b < 16928){           // uhw [256][128] -> uhwT [128][256]
    int idx = (b-16800)*256 + tid;
    int r = idx >> 7, c = idx & 127;
    uhwT[c*256 + r] = __float2bfloat16(uhw[idx]);
  } else if (b < 16992){           // uow [128][128] -> uowT [128][128]
    int idx = (b-16928)*256 + tid;
    int r = idx >> 7, c = idx & 127;
    uowT[c*128 + r] = __float2bfloat16(uow[idx]);
  } else if (b < 17120){           // v1w [128][256] -> v1wT [256][128]
    int idx = (b-16992)*256 + tid;
    int r = idx >> 8, c = idx & 255;
    v1wT[c*128 + r] = __float2bfloat16(v1w[idx]);
  } else {                         // v2w [256][256] -> v2wT [256][256]
    int idx = (b-17120)*256 + tid;
    int r = idx >> 8, c = idx & 255;
    v2wT[c*256 + r] = __float2bfloat16(v2w[idx]);
  }
}

__global__ __launch_bounds__(256)
void vout_k(const __hip_bfloat16* __restrict__ v2, const float* __restrict__ w,
            const float* __restrict__ b, float* __restrict__ values)
{
  int row  = blockIdx.x*4 + (threadIdx.x >> 6);
  int lane = threadIdx.x & 63;
  const ushort* vr = (const ushort*)v2 + (size_t)row*VH_;
  float s = 0.f;
  #pragma unroll
  for (int i=0;i<4;i++) s = fmaf(bu2f(vr[lane + 64*i]), w[lane + 64*i], s);
  #pragma unroll
  for (int off=32; off; off>>=1) s += __shfl_down(s, off);
  if (lane==0) values[row] = s + b[0];
}

extern "C" void kernel_launch(void* const* d_in, const int* in_sizes, int n_in,
                              void* d_out, int out_size, void* d_ws, size_t ws_size,
                              hipStream_t stream) {
  const float* hidden = (const float*)d_in[0];
  const float* obs    = (const float*)d_in[1];
  const int*   dones  = (const int*)  d_in[2];
  const float* e1w = (const float*)d_in[3];
  const float* e1b = (const float*)d_in[4];
  const float* e2w = (const float*)d_in[5];
  const float* e2b = (const float*)d_in[6];
  const float* gWi = (const float*)d_in[7];
  const float* gbi = (const float*)d_in[8];
  const float* gWh = (const float*)d_in[9];
  const float* gbhn= (const float*)d_in[10];
  const float* chw = (const float*)d_in[11];
  const float* chb = (const float*)d_in[12];
  const float* cow = (const float*)d_in[13];
  const float* cob = (const float*)d_in[14];
  const float* uhw = (const float*)d_in[15];
  const float* uhb = (const float*)d_in[16];
  const float* uow = (const float*)d_in[17];
  const float* uob = (const float*)d_in[18];
  const float* v1w = (const float*)d_in[19];
  const float* v1b = (const float*)d_in[20];
  const float* v2w = (const float*)d_in[21];
  const float* v2b = (const float*)d_in[22];
  const float* vow = (const float*)d_in[23];
  const float* vob = (const float*)d_in[24];
  (void)in_sizes; (void)n_in; (void)out_size;

  float* out_hidden = (float*)d_out;
  float* out_values = (float*)d_out + (size_t)B_*D_;

  // Arena (float-slot offsets). Peak 38.1M slots = 152 MB (ws >= 218 MB known).
  float* ws = (float*)d_ws;
  __hip_bfloat16* obsh  = (__hip_bfloat16*)(ws);             // [0, 2.10M)
  __hip_bfloat16* obsl  = (__hip_bfloat16*)(ws + 2097152);   // [2.10M, 4.19M)
  __hip_bfloat16* emb1h = (__hip_bfloat16*)(ws + 4194304);   // [4.19M, 8.39M)
  __hip_bfloat16* emb1l = (__hip_bfloat16*)(ws + 8388608);   // [8.39M, 12.58M)
  __hip_bfloat16* emb2h = (__hip_bfloat16*)(ws + 12582912);  // [12.58M, 16.78M)
  __hip_bfloat16* emb2l = (__hip_bfloat16*)(ws + 16777216);  // [16.78M, 20.97M)
  float* giA = ws;                                            // [0, 12.58M)  overlays obs+emb1
  float* giB = ws + 20971520;                                 // [20.97M, 33.55M)
  __hip_bfloat16* Xe    = (__hip_bfloat16*)(ws + 33554432);   // [33.55M, 37.75M) e bf16
  __hip_bfloat16* wb    = (__hip_bfloat16*)(ws + 37748736);   // weights (~332K slots-as-bf16)
  // post-GRU overlays (gi / emb regions dead):
  __hip_bfloat16* acatB = (__hip_bfloat16*)(ws);              // [0, 8.39M)
  __hip_bfloat16* Xc    = (__hip_bfloat16*)(ws + 8388608);    // [8.39M, 12.58M)
  __hip_bfloat16* Xd    = (__hip_bfloat16*)(ws + 12582912);   // [12.58M, 16.78M)
  __hip_bfloat16* v1b16 = (__hip_bfloat16*)(ws + 20971520);   // [20.97M, 29.36M)
  __hip_bfloat16* v2b16 = (__hip_bfloat16*)(ws);              // [0, 8.39M)  (acat dead)
  if (ws_size < (size_t)38100000 * sizeof(float)) return;

  __hip_bfloat16* bcatT = wb;             // [256][128]
  __hip_bfloat16* uhwT  = wb + 32768;     // [128][256]
  __hip_bfloat16* uowT  = wb + 65536;     // [128][128]
  __hip_bfloat16* v1wT  = wb + 81920;     // [256][128]
  __hip_bfloat16* v2wT  = wb + 114688;    // [256][256]
  __hip_bfloat16* e1wTh = wb + 180224;    // [128][64]
  __hip_bfloat16* e1wTl = wb + 188416;
  __hip_bfloat16* e2wTh = wb + 196608;    // [128][128]
  __hip_bfloat16* e2wTl = wb + 212992;
  __hip_bfloat16* gWiTh = wb + 229376;    // [384][128]
  __hip_bfloat16* gWiTl = wb + 278528;

  dim3 blk(256);
  packall_k<<<dim3(17376), blk, 0, stream>>>(
    obs, obsh, obsl, e1w, e1wTh, e1wTl, e2w, e2wTh, e2wTl, gWi, gWiTh, gWiTl,
    chw, bcatT, uhw, uhwT, uow, uowT, v1w, v1wT, v2w, v2wT);

  // embeds (split-precision, fp32-class)
  mgemm3_k<1,false,true><<<dim3(2,512), blk, 0, stream>>>(
    obsh, obsl, e1wTh, e1wTl, e1b, nullptr, emb1h, emb1l, M_, 128, 64);
  mgemm3_k<1,false,true><<<dim3(2,512), blk, 0, stream>>>(
    emb1h, emb1l, e2wTh, e2wTl, e2b, nullptr, emb2h, emb2l, M_, 128, 128);
  // gi in two halves (fp32 out)
  mgemm3_k<0,true,false><<<dim3(6,256), blk, 0, stream>>>(
    emb2h, emb2l, gWiTh, gWiTl, gbi, giA, nullptr, nullptr, M_/2, 384, 128);
  mgemm3_k<0,true,false><<<dim3(6,256), blk, 0, stream>>>(
    emb2h + (size_t)(M_/2)*D_, emb2l + (size_t)(M_/2)*D_, gWiTh, gWiTl, gbi, giB,
    nullptr, nullptr, M_/2, 384, 128);

  // MFMA GRU: broadcast A-reads, deferred e-store, 1 barrier/step
  grum7_k<<<dim3(128), dim3(512), 0, stream>>>(giA, giB, hidden, dones, gWh, gbhn, Xe, out_hidden);

  for (int it=0; it<2; it++){
    mgemm_k<0,false,false,false><<<dim3(2,512), blk, 0, stream>>>(
      Xe, nullptr, bcatT, nullptr, nullptr, nullptr, acatB, M_, 256, 128);
    couple_k<<<dim3(T_*NE_), blk, 0, stream>>>(acatB, Xe, chb, cow, cob, Xc);
    mgemm_k<1,true,false,false><<<dim3(1,512), blk, 0, stream>>>(
      Xe, Xc, uhwT, uhb, nullptr, nullptr, Xd, M_, 128, 256);
    mgemm_k<1,false,true,true><<<dim3(1,512), blk, 0, stream>>>(
      Xd, nullptr, uowT, uob, (const unsigned short*)Xe, dones, Xe, M_, 128, 128);
  }
  mgemm_k<1,false,false,false><<<dim3(2,512), blk, 0, stream>>>(
    Xe, nullptr, v1wT, v1b, nullptr, nullptr, v1b16, M_, 256, 128);
  mgemm_k<1,false,false,false><<<dim3(2,512), blk, 0, stream>>>(
    v1b16, nullptr, v2wT, v2b, nullptr, nullptr, v2b16, M_, 256, 256);
  vout_k<<<dim3(M_/4), blk, 0, stream>>>(v2b16, vow, vob, out_values);
}

// Round 12
// 441.817 us; speedup vs baseline: 1.2539x; 1.2539x over previous
//
#include <hip/hip_runtime.h>
#include <hip/hip_bf16.h>
#include <math.h>

#define T_ 128
#define NE_ 64
#define NA_ 8
#define B_ 512
#define OBS_ 64
#define D_ 128
#define CH_ 128
#define VH_ 256
#define M_ (T_*B_)   // 65536

typedef __attribute__((ext_vector_type(8))) short bf16x8;
typedef __attribute__((ext_vector_type(8))) _Float16 f16x8;
typedef __attribute__((ext_vector_type(4))) float f32x4;

__device__ __forceinline__ float sigmoidf_(float x){ return 1.f/(1.f+__expf(-x)); }
__device__ __forceinline__ unsigned short f2bu(float v){
  __hip_bfloat16 b = __float2bfloat16(v);
  return __builtin_bit_cast(unsigned short, b);
}
__device__ __forceinline__ float bu2f(unsigned short u){
  return __builtin_bit_cast(float, (unsigned int)u << 16);
}
__device__ __forceinline__ unsigned short f2hu(float v){
  _Float16 h = (_Float16)v;
  return __builtin_bit_cast(unsigned short, h);
}
__device__ __forceinline__ float hu2f(unsigned short u){
  return (float)__builtin_bit_cast(_Float16, u);
}
__device__ __forceinline__ float ulo(unsigned int u){ return __builtin_bit_cast(float, u << 16); }
__device__ __forceinline__ float uhi(unsigned int u){ return __builtin_bit_cast(float, u & 0xFFFF0000u); }

// ---------------------------------------------------------------------------
// fp16 MFMA GEMM (single-term): C_fp16 = epi(A_fp16[M][K] @ B + bias),
// BT = B^T [N][K] fp16. BM=128, BN=64, BK=64, 256 thr, wave tile 64x32.
// fp16 mantissa 2^-11: per-element rel error ~5e-4 — fits the 4.3e-3 budget.
// ---------------------------------------------------------------------------
template<int ACT>
__global__ __launch_bounds__(256)
void mgemmh_k(const ushort* __restrict__ A, const ushort* __restrict__ BT,
              const float* __restrict__ bias, ushort* __restrict__ C,
              int M, int N, int K)
{
  __shared__ ushort As[128*72];
  __shared__ ushort Bs[64*72];
  const int tid  = threadIdx.x;
  const int lane = tid & 63, wave = tid >> 6;
  const int wm = wave >> 1, wn = wave & 1;
  const int quad = lane >> 4, ln = lane & 15;
  const int n0 = blockIdx.x * 64;
  const int m0 = blockIdx.y * 128;

  f32x4 acc[4][2];
  #pragma unroll
  for (int i=0;i<4;i++)
    #pragma unroll
    for (int j=0;j<2;j++)
      #pragma unroll
      for (int r=0;r<4;r++) acc[i][j][r] = 0.f;

  for (int kc=0; kc<K; kc+=64){
    #pragma unroll
    for (int i=0;i<4;i++){
      int c8 = tid + i*256;
      int m = c8 >> 3, kq = (c8 & 7)*8;
      *(uint4*)&As[m*72+kq] = *(const uint4*)&A[(size_t)(m0+m)*K + kc + kq];
    }
    #pragma unroll
    for (int i=0;i<2;i++){
      int c8 = tid + i*256;
      int n = c8 >> 3, kq = (c8 & 7)*8;
      *(uint4*)&Bs[n*72+kq] = *(const uint4*)&BT[(size_t)(n0+n)*K + kc + kq];
    }
    __syncthreads();
    #pragma unroll
    for (int ks=0; ks<2; ks++){
      const int kq = ks*32 + quad*8;
      f16x8 af[4], bfv[2];
      #pragma unroll
      for (int mt=0;mt<4;mt++)
        af[mt] = *(const f16x8*)&As[(wm*64 + mt*16 + ln)*72 + kq];
      #pragma unroll
      for (int nt=0;nt<2;nt++)
        bfv[nt] = *(const f16x8*)&Bs[(wn*32 + nt*16 + ln)*72 + kq];
      #pragma unroll
      for (int mt=0;mt<4;mt++)
        #pragma unroll
        for (int nt=0;nt<2;nt++)
          acc[mt][nt] = __builtin_amdgcn_mfma_f32_16x16x32_f16(af[mt], bfv[nt], acc[mt][nt], 0,0,0);
    }
    __syncthreads();
  }

  float biasv[2];
  #pragma unroll
  for (int nt=0;nt<2;nt++) biasv[nt] = bias ? bias[n0 + wn*32 + nt*16 + ln] : 0.f;
  #pragma unroll
  for (int mt=0;mt<4;mt++){
    #pragma unroll
    for (int r=0;r<4;r++){
      int row = m0 + wm*64 + mt*16 + quad*4 + r;
      #pragma unroll
      for (int nt=0;nt<2;nt++){
        int col = n0 + wn*32 + nt*16 + ln;
        float v = acc[mt][nt][r] + biasv[nt];
        if (ACT==1) v = fmaxf(v, 0.f);
        C[(size_t)row*N + col] = f2hu(v);
      }
    }
  }
}

// ---------------------------------------------------------------------------
// bf16 MFMA GEMM (post-GRU): BT = B^T [N,K] bf16; 128x128 tile, BK=128.
// RESID: += bf16 resid AFTER act.  SCALE: *= alive.  Write bf16.
// ---------------------------------------------------------------------------
template<int ACT, bool DUAL, bool RESID, bool SCALE>
__global__ __launch_bounds__(256)
void mgemm_k(const __hip_bfloat16* __restrict__ A, const __hip_bfloat16* __restrict__ A2,
             const __hip_bfloat16* __restrict__ BT, const float* __restrict__ bias,
             const unsigned short* __restrict__ resid, const int* __restrict__ dones,
             __hip_bfloat16* __restrict__ Cb, int M, int N, int K)
{
  __shared__ ushort As[128*136];
  __shared__ ushort Bs[128*136];
  const int tid  = threadIdx.x;
  const int lane = tid & 63, wave = tid >> 6;
  const int wm = wave >> 1, wn = wave & 1;
  const int quad = lane >> 4, ln = lane & 15;
  const int n0 = blockIdx.x * 128;
  const int m0 = blockIdx.y * 128;

  f32x4 acc[4][4];
  #pragma unroll
  for (int i=0;i<4;i++)
    #pragma unroll
    for (int j=0;j<4;j++)
      #pragma unroll
      for (int r=0;r<4;r++) acc[i][j][r] = 0.f;

  for (int kc=0; kc<K; kc+=128){
    const __hip_bfloat16* Ab; int arow, akoff;
    if (DUAL) { Ab = kc ? A2 : A; arow = 128; akoff = 0; }
    else      { Ab = A;           arow = K;   akoff = kc; }
    #pragma unroll
    for (int i=0;i<8;i++){
      int c8 = tid + i*256;
      int m = c8 >> 4, kq = (c8 & 15)*8;
      *(uint4*)&As[m*136 + kq] = *(const uint4*)&Ab[(size_t)(m0+m)*arow + akoff + kq];
    }
    #pragma unroll
    for (int i=0;i<8;i++){
      int c8 = tid + i*256;
      int n = c8 >> 4, kq = (c8 & 15)*8;
      *(uint4*)&Bs[n*136 + kq] = *(const uint4*)&BT[(size_t)(n0+n)*K + kc + kq];
    }
    __syncthreads();
    #pragma unroll
    for (int ks=0; ks<4; ks++){
      const int kq = ks*32 + quad*8;
      bf16x8 af[4], bfv[4];
      #pragma unroll
      for (int mt=0;mt<4;mt++)
        af[mt] = *(const bf16x8*)&As[(wm*64 + mt*16 + ln)*136 + kq];
      #pragma unroll
      for (int nt=0;nt<4;nt++)
        bfv[nt] = *(const bf16x8*)&Bs[(wn*64 + nt*16 + ln)*136 + kq];
      #pragma unroll
      for (int mt=0;mt<4;mt++)
        #pragma unroll
        for (int nt=0;nt<4;nt++)
          acc[mt][nt] = __builtin_amdgcn_mfma_f32_16x16x32_bf16(af[mt], bfv[nt], acc[mt][nt], 0,0,0);
    }
    __syncthreads();
  }

  float biasv[4];
  #pragma unroll
  for (int nt=0;nt<4;nt++){
    int col = n0 + wn*64 + nt*16 + ln;
    biasv[nt] = bias ? bias[col] : 0.f;
  }
  #pragma unroll
  for (int mt=0;mt<4;mt++){
    #pragma unroll
    for (int r=0;r<4;r++){
      int row = m0 + wm*64 + mt*16 + quad*4 + r;
      float al = 1.f;
      if (SCALE) al = (dones[row]!=0) ? 0.f : 1.f;
      #pragma unroll
      for (int nt=0;nt<4;nt++){
        int col = n0 + wn*64 + nt*16 + ln;
        float v = acc[mt][nt][r] + biasv[nt];
        if (ACT==1) v = fmaxf(v, 0.f);
        if (RESID)  v += bu2f(resid[(size_t)row*N + col]);
        if (SCALE)  v *= al;
        Cb[(size_t)row*N + col] = __float2bfloat16(v);
      }
    }
  }
}

// ---------------------------------------------------------------------------
// MFMA GRU v8: single-term fp16. Rounds 10/11 proved the step is bound by
// issued-MFMA volume (36/wave = 1397 cyc floor; LDS conflicts/BW were
// irrelevant). fp16 (2^-11 mantissa) lets one term replace the 3-term bf16
// split: 12 MFMA/wave -> 465-cyc floor. gi is fp16 (halves the stream).
// Structure from v7: 128 blocks x 4 rows, broadcast A-reads (ln&12),
// in-wave gates, 1 barrier/step, deferred e-store, reset-carry semantics.
// ---------------------------------------------------------------------------
__global__ __launch_bounds__(512, 1)
void grum8_k(const ushort* __restrict__ gih, const float* __restrict__ hidden0,
             const int* __restrict__ dones, const float* __restrict__ gWh,
             const float* __restrict__ bhn, __hip_bfloat16* __restrict__ eb_out,
             float* __restrict__ hout)
{
  __shared__ ushort wstg[32*392];
  __shared__ ushort hb[2][16*136];
  __shared__ float  dnS[T_*4];
  const int tid  = threadIdx.x;
  const int lane = tid & 63, wave = tid >> 6;   // 8 waves
  const int quad = lane >> 4, ln = lane & 15;
  const int r0   = blockIdx.x * 4;
  const int col  = wave*16 + ln;      // h-dim owned by this lane
  const int lnb  = ln & 12;           // broadcast A-row (real rows 0,4,8,12)

  dnS[tid] = (dones[(size_t)(tid>>2)*B_ + r0 + (tid&3)] != 0) ? 1.f : 0.f;
  const float bhnr = bhn[col];

  for (int i=tid; i<16*136; i+=512){ hb[0][i]=0; hb[1][i]=0; }

  // Wh fp16 B-fragments in registers (cols g*128+col), staged via LDS
  f16x8 bf[3][4];
  #pragma unroll
  for (int kc=0; kc<4; kc++){
    for (int i=tid; i<32*384; i+=512){
      int kk = i/384, c = i - kk*384;
      wstg[kk*392 + c] = f2hu(gWh[(size_t)(kc*32+kk)*384 + c]);
    }
    __syncthreads();
    #pragma unroll
    for (int g=0; g<3; g++){
      int c = g*128 + col;
      ushort tmp[8];
      #pragma unroll
      for (int j=0;j<8;j++) tmp[j] = wstg[(quad*8+j)*392 + c];
      bf[g][kc] = *(const f16x8*)tmp;
    }
    __syncthreads();
  }

  // init h: lane owns (row=quad, dim=col); batch row q lives at A/C-row 4q
  float hc = hidden0[(size_t)(r0+quad)*D_ + col];
  if (dnS[quad] > 0.5f) hc = 0.f;
  hb[0][(quad*4)*136 + col] = f2hu(hc);
  __syncthreads();

  // prime gi[0] (fp16)
  float c_r, c_z, c_n;
  {
    const ushort* gp = gih + ((size_t)(r0+quad))*384;
    c_r = hu2f(gp[col]); c_z = hu2f(gp[col+128]); c_n = hu2f(gp[col+256]);
  }

  ushort pend_eu = 0;   // deferred e-store (written after the barrier)

  for (int t=0; t<T_; t++){
    if (t > 0)
      ((ushort*)eb_out)[((size_t)(t-1)*B_ + r0+quad)*D_ + col] = pend_eu;

    // distance-1 gi prefetch (fp16): drains free at end-of-step barrier
    float n_r=0.f, n_z=0.f, n_n=0.f;
    if (t+1 < T_){
      const ushort* gp = gih + ((size_t)(t+1)*B_ + r0+quad)*384;
      n_r = hu2f(gp[col]); n_z = hu2f(gp[col+128]); n_n = hu2f(gp[col+256]);
    }

    // MFMA phase: gh = h @ Wh, single fp16 term, broadcast A-reads
    const ushort* hbuf = hb[t&1];
    f32x4 acc[3];
    #pragma unroll
    for (int g=0;g<3;g++)
      #pragma unroll
      for (int r=0;r<4;r++) acc[g][r]=0.f;
    #pragma unroll
    for (int ks=0; ks<4; ks++){
      f16x8 ah = *(const f16x8*)&hbuf[lnb*136 + ks*32 + quad*8];
      #pragma unroll
      for (int g=0;g<3;g++)
        acc[g] = __builtin_amdgcn_mfma_f32_16x16x32_f16(ah, bf[g][ks], acc[g], 0,0,0);
    }

    // gate phase: fully in-wave; lane (quad,ln) reg 0 = its (row,dim)
    const float dnow  = dnS[t*4 + quad];
    const float dnext = (t+1 < T_) ? dnS[(t+1)*4 + quad] : 0.f;
    float rg = sigmoidf_(c_r + acc[0][0]);
    float zg = sigmoidf_(c_z + acc[1][0]);
    float x  = c_n + rg*(acc[2][0] + bhnr);
    float ng = 2.f/(1.f+__expf(-2.f*x)) - 1.f;   // tanh
    float hnew = (1.f - zg)*ng + zg*hc;
    pend_eu = f2bu(hnew*(1.f-dnow));
    float hv = (dnext > 0.5f) ? 0.f : hnew;
    hc = hv;                               // carry the RESET h
    hb[(t+1)&1][(quad*4)*136 + col] = f2hu(hv);
    __syncthreads();
    c_r = n_r; c_z = n_z; c_n = n_n;
  }
  ((ushort*)eb_out)[((size_t)(T_-1)*B_ + r0+quad)*D_ + col] = pend_eu;
  hout[(size_t)(r0+quad)*D_ + col] = hc;
}

// ---------------------------------------------------------------------------
// Coupling per (t,env), bf16 inputs: C_ij = sigmoid(relu(ai+aj+cb).w + cob),
// C_ii=0; ctx[i] = sum_j C_ij e[j] -> bf16.
// ---------------------------------------------------------------------------
__global__ __launch_bounds__(256)
void couple_k(const __hip_bfloat16* __restrict__ acat, const __hip_bfloat16* __restrict__ e,
              const float* __restrict__ chb, const float* __restrict__ cow,
              const float* __restrict__ cob, __hip_bfloat16* __restrict__ ctxb)
{
  __shared__ float ai[NA_][CH_], aj[NA_][CH_], es[NA_][D_], cbw[CH_], cww[CH_], Cs[NA_][NA_];
  const int m0 = blockIdx.x * NA_;
  const int tid = threadIdx.x;

  {
    int j = tid >> 5, q = (tid & 31)*8;
    uint4 u = *(const uint4*)((const ushort*)acat + (size_t)(m0+j)*256 + q);
    float f[8] = {ulo(u.x),uhi(u.x),ulo(u.y),uhi(u.y),ulo(u.z),uhi(u.z),ulo(u.w),uhi(u.w)};
    float* dst = (q < 128) ? &ai[j][q] : &aj[j][q-128];
    #pragma unroll
    for (int i=0;i<8;i++) dst[i] = f[i];
  }
  if (tid < 128){
    int j = tid >> 4, q = (tid & 15)*8;
    uint4 u = *(const uint4*)((const ushort*)e + (size_t)(m0+j)*D_ + q);
    float f[8] = {ulo(u.x),uhi(u.x),ulo(u.y),uhi(u.y),ulo(u.z),uhi(u.z),ulo(u.w),uhi(u.w)};
    #pragma unroll
    for (int i=0;i<8;i++) es[j][q+i] = f[i];
    cbw[tid] = chb[tid]; cww[tid] = cow[tid];
  }
  __syncthreads();

  {
    int p = tid >> 2, q = tid & 3;
    int i = p >> 3, j = p & 7;
    float s = 0.f;
    #pragma unroll
    for (int h = 0; h < 32; h++){
      int hh = q*32 + h;
      s += fmaxf(ai[i][hh] + aj[j][hh] + cbw[hh], 0.f) * cww[hh];
    }
    s += __shfl_down(s, 2);
    s += __shfl_down(s, 1);
    if (q == 0) {
      float Cv = sigmoidf_(s + cob[0]);
      Cs[i][j] = (i==j) ? 0.f : Cv;
    }
  }
  __syncthreads();
  #pragma unroll
  for (int rep=0; rep<4; rep++){
    int idx = rep*256 + tid;
    int i = idx >> 7, d = idx & 127;
    float s = 0.f;
    #pragma unroll
    for (int j=0;j<NA_;j++) s = fmaf(Cs[i][j], es[j][d], s);
    ctxb[(size_t)(m0+i)*D_ + d] = __float2bfloat16(s);
  }
}

// ---------------------------------------------------------------------------
// Fused preamble (one dispatch): obs->fp16, pre-GRU weights->fp16-transposed,
// post-GRU weights->bf16-transposed.
// Ranges: [0,16384) obs | [16384,16416) e1w | [16416,16480) e2w |
// [16480,16672) gWi | [16672,16800) bcat | [16800,16928) uhw |
// [16928,16992) uow | [16992,17120) v1w | [17120,17376) v2w
// ---------------------------------------------------------------------------
__global__ __launch_bounds__(256)
void packall_k(const float* __restrict__ obs, ushort* __restrict__ obsH,
               const float* __restrict__ e1w, ushort* __restrict__ e1T,
               const float* __restrict__ e2w, ushort* __restrict__ e2T,
               const float* __restrict__ gWi, ushort* __restrict__ giT,
               const float* __restrict__ chw, __hip_bfloat16* __restrict__ bcatT,
               const float* __restrict__ uhw, __hip_bfloat16* __restrict__ uhwT,
               const float* __restrict__ uow, __hip_bfloat16* __restrict__ uowT,
               const float* __restrict__ v1w, __hip_bfloat16* __restrict__ v1wT,
               const float* __restrict__ v2w, __hip_bfloat16* __restrict__ v2wT)
{
  const int b = blockIdx.x, tid = threadIdx.x;
  if (b < 16384){
    int idx = b*256 + tid;
    obsH[idx] = f2hu(obs[idx]);
  } else if (b < 16416){           // e1w [64][128] -> [128][64] fp16
    int idx = (b-16384)*256 + tid;
    int n = idx >> 6, k = idx & 63;
    e1T[idx] = f2hu(e1w[k*128 + n]);
  } else if (b < 16480){           // e2w [128][128] -> [128][128] fp16
    int idx = (b-16416)*256 + tid;
    int n = idx >> 7, k = idx & 127;
    e2T[idx] = f2hu(e2w[k*128 + n]);
  } else if (b < 16672){           // gWi [128][384] -> [384][128] fp16
    int idx = (b-16480)*256 + tid;
    int n = idx >> 7, k = idx & 127;
    giT[idx] = f2hu(gWi[k*384 + n]);
  } else if (b < 16800){           // bcatT [256][128] bf16
    int idx = (b-16672)*256 + tid;
    int n = idx >> 7, k = idx & 127;
    float v = (n < 128) ? chw[k*128 + n] : chw[(128+k)*128 + (n-128)];
    bcatT[idx] = __float2bfloat16(v);
  } else if (b < 16928){           // uhw [256][128] -> uhwT [128][256]
    int idx = (b-16800)*256 + tid;
    int r = idx >> 7, c = idx & 127;
    uhwT[c*256 + r] = __float2bfloat16(uhw[idx]);
  } else if (b < 16992){           // uow [128][128] -> uowT [128][128]
    int idx = (b-16928)*256 + tid;
    int r = idx >> 7, c = idx & 127;
    uowT[c*128 + r] = __float2bfloat16(uow[idx]);
  } else if (b < 17120){           // v1w [128][256] -> v1wT [256][128]
    int idx = (b-16992)*256 + tid;
    int r = idx >> 8, c = idx & 255;
    v1wT[c*128 + r] = __float2bfloat16(v1w[idx]);
  } else {                         // v2w [256][256] -> v2wT [256][256]
    int idx = (b-17120)*256 + tid;
    int r = idx >> 8, c = idx & 255;
    v2wT[c*256 + r] = __float2bfloat16(v2w[idx]);
  }
}

__global__ __launch_bounds__(256)
void vout_k(const __hip_bfloat16* __restrict__ v2, const float* __restrict__ w,
            const float* __restrict__ b, float* __restrict__ values)
{
  int row  = blockIdx.x*4 + (threadIdx.x >> 6);
  int lane = threadIdx.x & 63;
  const ushort* vr = (const ushort*)v2 + (size_t)row*VH_;
  float s = 0.f;
  #pragma unroll
  for (int i=0;i<4;i++) s = fmaf(bu2f(vr[lane + 64*i]), w[lane + 64*i], s);
  #pragma unroll
  for (int off=32; off; off>>=1) s += __shfl_down(s, off);
  if (lane==0) values[row] = s + b[0];
}

extern "C" void kernel_launch(void* const* d_in, const int* in_sizes, int n_in,
                              void* d_out, int out_size, void* d_ws, size_t ws_size,
                              hipStream_t stream) {
  const float* hidden = (const float*)d_in[0];
  const float* obs    = (const float*)d_in[1];
  const int*   dones  = (const int*)  d_in[2];
  const float* e1w = (const float*)d_in[3];
  const float* e1b = (const float*)d_in[4];
  const float* e2w = (const float*)d_in[5];
  const float* e2b = (const float*)d_in[6];
  const float* gWi = (const float*)d_in[7];
  const float* gbi = (const float*)d_in[8];
  const float* gWh = (const float*)d_in[9];
  const float* gbhn= (const float*)d_in[10];
  const float* chw = (const float*)d_in[11];
  const float* chb = (const float*)d_in[12];
  const float* cow = (const float*)d_in[13];
  const float* cob = (const float*)d_in[14];
  const float* uhw = (const float*)d_in[15];
  const float* uhb = (const float*)d_in[16];
  const float* uow = (const float*)d_in[17];
  const float* uob = (const float*)d_in[18];
  const float* v1w = (const float*)d_in[19];
  const float* v1b = (const float*)d_in[20];
  const float* v2w = (const float*)d_in[21];
  const float* v2b = (const float*)d_in[22];
  const float* vow = (const float*)d_in[23];
  const float* vob = (const float*)d_in[24];
  (void)in_sizes; (void)n_in; (void)out_size;

  float* out_hidden = (float*)d_out;
  float* out_values = (float*)d_out + (size_t)B_*D_;

  // Arena (float-slot offsets). Peak ~27.4M slots = 110 MB (ws >= 210 MB known).
  float* ws = (float*)d_ws;
  ushort* obsH  = (ushort*)(ws);                      // [0, 2.10M)  fp16 M*64
  ushort* emb1H = (ushort*)(ws + 2097152);            // [2.10M, 6.29M)  fp16 M*128
  ushort* emb2H = (ushort*)(ws + 6291456);            // [6.29M, 10.49M) fp16 M*128
  ushort* giH   = (ushort*)(ws + 10485760);           // [10.49M, 23.07M) fp16 M*384
  __hip_bfloat16* Xe = (__hip_bfloat16*)(ws + 23068672); // [23.07M, 27.26M) e bf16
  ushort* wb    = (ushort*)(ws + 27262976);           // weights (~254K ushorts)
  // post-GRU overlays (obs/emb/gi regions dead after grum):
  __hip_bfloat16* acatB = (__hip_bfloat16*)(ws);              // [0, 8.39M)
  __hip_bfloat16* Xc    = (__hip_bfloat16*)(ws + 8388608);    // [8.39M, 12.58M)
  __hip_bfloat16* Xd    = (__hip_bfloat16*)(ws + 12582912);   // [12.58M, 16.78M)
  __hip_bfloat16* v1b16 = (__hip_bfloat16*)(ws);              // [0, 8.39M)  (acat dead)
  __hip_bfloat16* v2b16 = (__hip_bfloat16*)(ws + 12582912);   // [12.58M, 20.97M)
  if (ws_size < (size_t)27500000 * sizeof(float)) return;

  __hip_bfloat16* bcatT = (__hip_bfloat16*)wb;        // [256][128]
  __hip_bfloat16* uhwT  = (__hip_bfloat16*)wb + 32768;   // [128][256]
  __hip_bfloat16* uowT  = (__hip_bfloat16*)wb + 65536;   // [128][128]
  __hip_bfloat16* v1wT  = (__hip_bfloat16*)wb + 81920;   // [256][128]
  __hip_bfloat16* v2wT  = (__hip_bfloat16*)wb + 114688;  // [256][256]
  ushort* e1wT = wb + 180224;   // [128][64]  fp16
  ushort* e2wT = wb + 188416;   // [128][128] fp16
  ushort* gWiT = wb + 204800;   // [384][128] fp16

  dim3 blk(256);
  packall_k<<<dim3(17376), blk, 0, stream>>>(
    obs, obsH, e1w, e1wT, e2w, e2wT, gWi, gWiT,
    chw, bcatT, uhw, uhwT, uow, uowT, v1w, v1wT, v2w, v2wT);

  // embeds + gi: single-term fp16 MFMA
  mgemmh_k<1><<<dim3(2,512), blk, 0, stream>>>(obsH,  e1wT, e1b, emb1H, M_, 128, 64);
  mgemmh_k<1><<<dim3(2,512), blk, 0, stream>>>(emb1H, e2wT, e2b, emb2H, M_, 128, 128);
  mgemmh_k<0><<<dim3(6,512), blk, 0, stream>>>(emb2H, gWiT, gbi, giH,   M_, 384, 128);

  // MFMA GRU: fp16 single-term, 12 MFMA/wave, 1 barrier/step
  grum8_k<<<dim3(128), dim3(512), 0, stream>>>(giH, hidden, dones, gWh, gbhn, Xe, out_hidden);

  for (int it=0; it<2; it++){
    mgemm_k<0,false,false,false><<<dim3(2,512), blk, 0, stream>>>(
      Xe, nullptr, bcatT, nullptr, nullptr, nullptr, acatB, M_, 256, 128);
    couple_k<<<dim3(T_*NE_), blk, 0, stream>>>(acatB, Xe, chb, cow, cob, Xc);
    mgemm_k<1,true,false,false><<<dim3(1,512), blk, 0, stream>>>(
      Xe, Xc, uhwT, uhb, nullptr, nullptr, Xd, M_, 128, 256);
    mgemm_k<1,false,true,true><<<dim3(1,512), blk, 0, stream>>>(
      Xd, nullptr, uowT, uob, (const unsigned short*)Xe, dones, Xe, M_, 128, 128);
  }
  mgemm_k<1,false,false,false><<<dim3(2,512), blk, 0, stream>>>(
    Xe, nullptr, v1wT, v1b, nullptr, nullptr, v1b16, M_, 256, 128);
  mgemm_k<1,false,false,false><<<dim3(2,512), blk, 0, stream>>>(
    v1b16, nullptr, v2wT, v2b, nullptr, nullptr, v2b16, M_, 256, 256);
  vout_k<<<dim3(M_/4), blk, 0, stream>>>(v2b16, vow, vob, out_values);
}

// Round 13
// 428.778 us; speedup vs baseline: 1.2920x; 1.0304x over previous
//
#include <hip/hip_runtime.h>
#include <hip/hip_bf16.h>
#include <math.h>

#define T_ 128
#define NE_ 64
#define NA_ 8
#define B_ 512
#define OBS_ 64
#define D_ 128
#define CH_ 128
#define VH_ 256
#define M_ (T_*B_)   // 65536

typedef __attribute__((ext_vector_type(8))) short bf16x8;
typedef __attribute__((ext_vector_type(8))) _Float16 f16x8;
typedef __attribute__((ext_vector_type(4))) float f32x4;

__device__ __forceinline__ float sigmoidf_(float x){ return 1.f/(1.f+__expf(-x)); }
__device__ __forceinline__ unsigned short f2bu(float v){
  __hip_bfloat16 b = __float2bfloat16(v);
  return __builtin_bit_cast(unsigned short, b);
}
__device__ __forceinline__ float bu2f(unsigned short u){
  return __builtin_bit_cast(float, (unsigned int)u << 16);
}
__device__ __forceinline__ unsigned short f2hu(float v){
  _Float16 h = (_Float16)v;
  return __builtin_bit_cast(unsigned short, h);
}
__device__ __forceinline__ float hu2f(unsigned short u){
  return (float)__builtin_bit_cast(_Float16, u);
}

// ---------------------------------------------------------------------------
// fp16 MFMA GEMM (single-term): C_fp16 = epi(A_fp16[M][K] @ B + bias)
// ---------------------------------------------------------------------------
template<int ACT>
__global__ __launch_bounds__(256)
void mgemmh_k(const ushort* __restrict__ A, const ushort* __restrict__ BT,
              const float* __restrict__ bias, ushort* __restrict__ C,
              int M, int N, int K)
{
  __shared__ ushort As[128*72];
  __shared__ ushort Bs[64*72];
  const int tid  = threadIdx.x;
  const int lane = tid & 63, wave = tid >> 6;
  const int wm = wave >> 1, wn = wave & 1;
  const int quad = lane >> 4, ln = lane & 15;
  const int n0 = blockIdx.x * 64;
  const int m0 = blockIdx.y * 128;

  f32x4 acc[4][2];
  #pragma unroll
  for (int i=0;i<4;i++)
    #pragma unroll
    for (int j=0;j<2;j++)
      #pragma unroll
      for (int r=0;r<4;r++) acc[i][j][r] = 0.f;

  for (int kc=0; kc<K; kc+=64){
    #pragma unroll
    for (int i=0;i<4;i++){
      int c8 = tid + i*256;
      int m = c8 >> 3, kq = (c8 & 7)*8;
      *(uint4*)&As[m*72+kq] = *(const uint4*)&A[(size_t)(m0+m)*K + kc + kq];
    }
    #pragma unroll
    for (int i=0;i<2;i++){
      int c8 = tid + i*256;
      int n = c8 >> 3, kq = (c8 & 7)*8;
      *(uint4*)&Bs[n*72+kq] = *(const uint4*)&BT[(size_t)(n0+n)*K + kc + kq];
    }
    __syncthreads();
    #pragma unroll
    for (int ks=0; ks<2; ks++){
      const int kq = ks*32 + quad*8;
      f16x8 af[4], bfv[2];
      #pragma unroll
      for (int mt=0;mt<4;mt++)
        af[mt] = *(const f16x8*)&As[(wm*64 + mt*16 + ln)*72 + kq];
      #pragma unroll
      for (int nt=0;nt<2;nt++)
        bfv[nt] = *(const f16x8*)&Bs[(wn*32 + nt*16 + ln)*72 + kq];
      #pragma unroll
      for (int mt=0;mt<4;mt++)
        #pragma unroll
        for (int nt=0;nt<2;nt++)
          acc[mt][nt] = __builtin_amdgcn_mfma_f32_16x16x32_f16(af[mt], bfv[nt], acc[mt][nt], 0,0,0);
    }
    __syncthreads();
  }

  float biasv[2];
  #pragma unroll
  for (int nt=0;nt<2;nt++) biasv[nt] = bias ? bias[n0 + wn*32 + nt*16 + ln] : 0.f;
  #pragma unroll
  for (int mt=0;mt<4;mt++){
    #pragma unroll
    for (int r=0;r<4;r++){
      int row = m0 + wm*64 + mt*16 + quad*4 + r;
      #pragma unroll
      for (int nt=0;nt<2;nt++){
        int col = n0 + wn*32 + nt*16 + ln;
        float v = acc[mt][nt][r] + biasv[nt];
        if (ACT==1) v = fmaxf(v, 0.f);
        C[(size_t)row*N + col] = f2hu(v);
      }
    }
  }
}

// ---------------------------------------------------------------------------
// bf16 MFMA GEMM (v1 head): BT = B^T [N,K] bf16; 128x128 tile, BK=128.
// ---------------------------------------------------------------------------
template<int ACT>
__global__ __launch_bounds__(256)
void mgemm_k(const __hip_bfloat16* __restrict__ A, const __hip_bfloat16* __restrict__ BT,
             const float* __restrict__ bias, __hip_bfloat16* __restrict__ Cb,
             int M, int N, int K)
{
  __shared__ ushort As[128*136];
  __shared__ ushort Bs[128*136];
  const int tid  = threadIdx.x;
  const int lane = tid & 63, wave = tid >> 6;
  const int wm = wave >> 1, wn = wave & 1;
  const int quad = lane >> 4, ln = lane & 15;
  const int n0 = blockIdx.x * 128;
  const int m0 = blockIdx.y * 128;

  f32x4 acc[4][4];
  #pragma unroll
  for (int i=0;i<4;i++)
    #pragma unroll
    for (int j=0;j<4;j++)
      #pragma unroll
      for (int r=0;r<4;r++) acc[i][j][r] = 0.f;

  for (int kc=0; kc<K; kc+=128){
    #pragma unroll
    for (int i=0;i<8;i++){
      int c8 = tid + i*256;
      int m = c8 >> 4, kq = (c8 & 15)*8;
      *(uint4*)&As[m*136 + kq] = *(const uint4*)&A[(size_t)(m0+m)*K + kc + kq];
    }
    #pragma unroll
    for (int i=0;i<8;i++){
      int c8 = tid + i*256;
      int n = c8 >> 4, kq = (c8 & 15)*8;
      *(uint4*)&Bs[n*136 + kq] = *(const uint4*)&BT[(size_t)(n0+n)*K + kc + kq];
    }
    __syncthreads();
    #pragma unroll
    for (int ks=0; ks<4; ks++){
      const int kq = ks*32 + quad*8;
      bf16x8 af[4], bfv[4];
      #pragma unroll
      for (int mt=0;mt<4;mt++)
        af[mt] = *(const bf16x8*)&As[(wm*64 + mt*16 + ln)*136 + kq];
      #pragma unroll
      for (int nt=0;nt<4;nt++)
        bfv[nt] = *(const bf16x8*)&Bs[(wn*64 + nt*16 + ln)*136 + kq];
      #pragma unroll
      for (int mt=0;mt<4;mt++)
        #pragma unroll
        for (int nt=0;nt<4;nt++)
          acc[mt][nt] = __builtin_amdgcn_mfma_f32_16x16x32_bf16(af[mt], bfv[nt], acc[mt][nt], 0,0,0);
    }
    __syncthreads();
  }

  float biasv[4];
  #pragma unroll
  for (int nt=0;nt<4;nt++) biasv[nt] = bias ? bias[n0 + wn*64 + nt*16 + ln] : 0.f;
  #pragma unroll
  for (int mt=0;mt<4;mt++){
    #pragma unroll
    for (int r=0;r<4;r++){
      int row = m0 + wm*64 + mt*16 + quad*4 + r;
      #pragma unroll
      for (int nt=0;nt<4;nt++){
        int col = n0 + wn*64 + nt*16 + ln;
        float v = acc[mt][nt][r] + biasv[nt];
        if (ACT==1) v = fmaxf(v, 0.f);
        Cb[(size_t)row*N + col] = __float2bfloat16(v);
      }
    }
  }
}

// ---------------------------------------------------------------------------
// Fused dpre+update: per 128-row block:
//   dpre = relu([Xe|Xc] @ uhwT + uhb)  (K=256, accumulated; tile kept in LDS)
//   Xe   = (Xe + relu(dpre @ uowT + uob)) * alive
// Saves the Xd round-trip (32 MB/iter) and one dispatch.
// ---------------------------------------------------------------------------
__global__ __launch_bounds__(256)
void updf_k(const __hip_bfloat16* __restrict__ Xe, const __hip_bfloat16* __restrict__ Xc,
            const __hip_bfloat16* __restrict__ uhwT, const float* __restrict__ uhb,
            const __hip_bfloat16* __restrict__ uowT, const float* __restrict__ uob,
            const int* __restrict__ dones, __hip_bfloat16* __restrict__ XeOut)
{
  __shared__ ushort As[128*136];   // A-stage, then dpre tile
  __shared__ ushort Bs[128*136];
  const int tid  = threadIdx.x;
  const int lane = tid & 63, wave = tid >> 6;
  const int wm = wave >> 1, wn = wave & 1;
  const int quad = lane >> 4, ln = lane & 15;
  const int m0 = blockIdx.x * 128;

  f32x4 acc[4][4];
  #pragma unroll
  for (int i=0;i<4;i++)
    #pragma unroll
    for (int j=0;j<4;j++)
      #pragma unroll
      for (int r=0;r<4;r++) acc[i][j][r] = 0.f;

  // phase 1: dpre accumulate over K=256 (kc=0: Xe, kc=1: Xc)
  for (int kc=0; kc<2; kc++){
    const __hip_bfloat16* Ab = kc ? Xc : Xe;
    #pragma unroll
    for (int i=0;i<8;i++){
      int c8 = tid + i*256;
      int m = c8 >> 4, kq = (c8 & 15)*8;
      *(uint4*)&As[m*136 + kq] = *(const uint4*)&Ab[(size_t)(m0+m)*128 + kq];
    }
    #pragma unroll
    for (int i=0;i<8;i++){
      int c8 = tid + i*256;
      int n = c8 >> 4, kq = (c8 & 15)*8;
      *(uint4*)&Bs[n*136 + kq] = *(const uint4*)&uhwT[(size_t)n*256 + kc*128 + kq];
    }
    __syncthreads();
    #pragma unroll
    for (int ks=0; ks<4; ks++){
      const int kq = ks*32 + quad*8;
      bf16x8 af[4], bfv[4];
      #pragma unroll
      for (int mt=0;mt<4;mt++)
        af[mt] = *(const bf16x8*)&As[(wm*64 + mt*16 + ln)*136 + kq];
      #pragma unroll
      for (int nt=0;nt<4;nt++)
        bfv[nt] = *(const bf16x8*)&Bs[(wn*64 + nt*16 + ln)*136 + kq];
      #pragma unroll
      for (int mt=0;mt<4;mt++)
        #pragma unroll
        for (int nt=0;nt<4;nt++)
          acc[mt][nt] = __builtin_amdgcn_mfma_f32_16x16x32_bf16(af[mt], bfv[nt], acc[mt][nt], 0,0,0);
    }
    __syncthreads();
  }

  // stage uowT -> Bs, and dpre epilogue -> As (both free after last barrier)
  #pragma unroll
  for (int i=0;i<8;i++){
    int c8 = tid + i*256;
    int n = c8 >> 4, kq = (c8 & 15)*8;
    *(uint4*)&Bs[n*136 + kq] = *(const uint4*)&uowT[(size_t)n*128 + kq];
  }
  #pragma unroll
  for (int mt=0;mt<4;mt++){
    #pragma unroll
    for (int r=0;r<4;r++){
      int rl = wm*64 + mt*16 + quad*4 + r;
      #pragma unroll
      for (int nt=0;nt<4;nt++){
        int cl = wn*64 + nt*16 + ln;
        float v = fmaxf(acc[mt][nt][r] + uhb[cl], 0.f);
        As[rl*136 + cl] = f2bu(v);
      }
    }
  }
  __syncthreads();

  // phase 2: e = (e + relu(dpre @ uowT + uob)) * alive
  f32x4 acc2[4][4];
  #pragma unroll
  for (int i=0;i<4;i++)
    #pragma unroll
    for (int j=0;j<4;j++)
      #pragma unroll
      for (int r=0;r<4;r++) acc2[i][j][r] = 0.f;
  #pragma unroll
  for (int ks=0; ks<4; ks++){
    const int kq = ks*32 + quad*8;
    bf16x8 af[4], bfv[4];
    #pragma unroll
    for (int mt=0;mt<4;mt++)
      af[mt] = *(const bf16x8*)&As[(wm*64 + mt*16 + ln)*136 + kq];
    #pragma unroll
    for (int nt=0;nt<4;nt++)
      bfv[nt] = *(const bf16x8*)&Bs[(wn*64 + nt*16 + ln)*136 + kq];
    #pragma unroll
    for (int mt=0;mt<4;mt++)
      #pragma unroll
      for (int nt=0;nt<4;nt++)
        acc2[mt][nt] = __builtin_amdgcn_mfma_f32_16x16x32_bf16(af[mt], bfv[nt], acc2[mt][nt], 0,0,0);
  }
  #pragma unroll
  for (int mt=0;mt<4;mt++){
    #pragma unroll
    for (int r=0;r<4;r++){
      int row = m0 + wm*64 + mt*16 + quad*4 + r;
      float al = (dones[row]!=0) ? 0.f : 1.f;
      #pragma unroll
      for (int nt=0;nt<4;nt++){
        int cl = wn*64 + nt*16 + ln;
        float v = fmaxf(acc2[mt][nt][r] + uob[cl], 0.f);
        v += bu2f(((const ushort*)Xe)[(size_t)row*128 + cl]);
        v *= al;
        XeOut[(size_t)row*128 + cl] = __float2bfloat16(v);
      }
    }
  }
}

// ---------------------------------------------------------------------------
// Fused acat+coupling per (t,env): block computes its 8x256 acat tile with
// MFMA (A-rows broadcast from the 8 real e rows; fp32 accumulate), then
// C_ij = sigmoid(relu(ai+aj+cb).w + cob), C_ii=0; ctx = C @ e -> bf16.
// Kills the separate acat GEMM and its 67 MB/iter round-trip.
// ---------------------------------------------------------------------------
__global__ __launch_bounds__(256)
void couple2_k(const __hip_bfloat16* __restrict__ Xe, const ushort* __restrict__ bcatT,
               const float* __restrict__ chb, const float* __restrict__ cow,
               const float* __restrict__ cob, __hip_bfloat16* __restrict__ ctxb)
{
  __shared__ ushort es16[8*136];
  __shared__ float ai[8][132], aj[8][132];
  __shared__ float cbw[CH_], cww[CH_], Cs[NA_][NA_];
  const int m0 = blockIdx.x * NA_;
  const int tid = threadIdx.x;
  const int lane = tid & 63, wave = tid >> 6;  // 4 waves
  const int quad = lane >> 4, ln = lane & 15;

  if (tid < 128){
    int j = tid >> 4, q = (tid & 15)*8;
    *(uint4*)&es16[j*136 + q] = *(const uint4*)((const ushort*)Xe + (size_t)(m0+j)*D_ + q);
    cbw[tid] = chb[tid]; cww[tid] = cow[tid];
  }
  __syncthreads();

  // acat MFMA: wave w covers cols w*64..w*64+63 (4 n-tiles)
  f32x4 acc[4];
  #pragma unroll
  for (int nt=0;nt<4;nt++)
    #pragma unroll
    for (int r=0;r<4;r++) acc[nt][r] = 0.f;
  #pragma unroll
  for (int ks=0; ks<4; ks++){
    bf16x8 af = *(const bf16x8*)&es16[(ln & 7)*136 + ks*32 + quad*8];
    #pragma unroll
    for (int nt=0;nt<4;nt++){
      int n = wave*64 + nt*16 + ln;
      bf16x8 bfv = *(const bf16x8*)&bcatT[(size_t)n*128 + ks*32 + quad*8];
      acc[nt] = __builtin_amdgcn_mfma_f32_16x16x32_bf16(af, bfv, acc[nt], 0,0,0);
    }
  }
  if (quad < 2){        // rows 0..7 live in quads 0,1
    #pragma unroll
    for (int nt=0;nt<4;nt++){
      int col = wave*64 + nt*16 + ln;
      #pragma unroll
      for (int r=0;r<4;r++){
        int row = quad*4 + r;
        float v = acc[nt][r];
        if (col < 128) ai[row][col] = v; else aj[row][col-128] = v;
      }
    }
  }
  __syncthreads();

  {
    int p = tid >> 2, q = tid & 3;
    int i = p >> 3, j = p & 7;
    float s = 0.f;
    #pragma unroll
    for (int h = 0; h < 32; h++){
      int hh = q*32 + h;
      s += fmaxf(ai[i][hh] + aj[j][hh] + cbw[hh], 0.f) * cww[hh];
    }
    s += __shfl_down(s, 2);
    s += __shfl_down(s, 1);
    if (q == 0) {
      float Cv = sigmoidf_(s + cob[0]);
      Cs[i][j] = (i==j) ? 0.f : Cv;
    }
  }
  __syncthreads();
  #pragma unroll
  for (int rep=0; rep<4; rep++){
    int idx = rep*256 + tid;
    int i = idx >> 7, d = idx & 127;
    float s = 0.f;
    #pragma unroll
    for (int j=0;j<NA_;j++) s = fmaf(Cs[i][j], bu2f(es16[j*136 + d]), s);
    ctxb[(size_t)(m0+i)*D_ + d] = __float2bfloat16(s);
  }
}

// ---------------------------------------------------------------------------
// Fused v2 + vout: per 128x128 tile compute v = relu(v1 @ v2wT + v2b),
// dot rows with vow in-register (xor-shuffle over ln), atomicAdd to values.
// vob added once by the (bx==0, wn==0) waves. values must be zeroed first.
// ---------------------------------------------------------------------------
__global__ __launch_bounds__(256)
void vhead2_k(const __hip_bfloat16* __restrict__ v1, const __hip_bfloat16* __restrict__ v2wT,
              const float* __restrict__ v2b, const float* __restrict__ vow,
              const float* __restrict__ vob, float* __restrict__ values)
{
  __shared__ ushort As[128*136];
  __shared__ ushort Bs[128*136];
  const int tid  = threadIdx.x;
  const int lane = tid & 63, wave = tid >> 6;
  const int wm = wave >> 1, wn = wave & 1;
  const int quad = lane >> 4, ln = lane & 15;
  const int n0 = blockIdx.x * 128;
  const int m0 = blockIdx.y * 128;

  f32x4 acc[4][4];
  #pragma unroll
  for (int i=0;i<4;i++)
    #pragma unroll
    for (int j=0;j<4;j++)
      #pragma unroll
      for (int r=0;r<4;r++) acc[i][j][r] = 0.f;

  for (int kc=0; kc<2; kc++){
    #pragma unroll
    for (int i=0;i<8;i++){
      int c8 = tid + i*256;
      int m = c8 >> 4, kq = (c8 & 15)*8;
      *(uint4*)&As[m*136 + kq] = *(const uint4*)((const ushort*)v1 + (size_t)(m0+m)*256 + kc*128 + kq);
    }
    #pragma unroll
    for (int i=0;i<8;i++){
      int c8 = tid + i*256;
      int n = c8 >> 4, kq = (c8 & 15)*8;
      *(uint4*)&Bs[n*136 + kq] = *(const uint4*)((const ushort*)v2wT + (size_t)(n0+n)*256 + kc*128 + kq);
    }
    __syncthreads();
    #pragma unroll
    for (int ks=0; ks<4; ks++){
      const int kq = ks*32 + quad*8;
      bf16x8 af[4], bfv[4];
      #pragma unroll
      for (int mt=0;mt<4;mt++)
        af[mt] = *(const bf16x8*)&As[(wm*64 + mt*16 + ln)*136 + kq];
      #pragma unroll
      for (int nt=0;nt<4;nt++)
        bfv[nt] = *(const bf16x8*)&Bs[(wn*64 + nt*16 + ln)*136 + kq];
      #pragma unroll
      for (int mt=0;mt<4;mt++)
        #pragma unroll
        for (int nt=0;nt<4;nt++)
          acc[mt][nt] = __builtin_amdgcn_mfma_f32_16x16x32_bf16(af[mt], bfv[nt], acc[mt][nt], 0,0,0);
    }
    __syncthreads();
  }

  float v2bv[4], voww[4];
  #pragma unroll
  for (int nt=0;nt<4;nt++){
    int col = n0 + wn*64 + nt*16 + ln;
    v2bv[nt] = v2b[col];
    voww[nt] = vow[col];
  }
  float s[4][4];
  #pragma unroll
  for (int mt=0;mt<4;mt++)
    #pragma unroll
    for (int r=0;r<4;r++){
      float p = 0.f;
      #pragma unroll
      for (int nt=0;nt<4;nt++)
        p += fmaxf(acc[mt][nt][r] + v2bv[nt], 0.f) * voww[nt];
      s[mt][r] = p;
    }
  #pragma unroll
  for (int off=1; off<16; off<<=1)
    #pragma unroll
    for (int mt=0;mt<4;mt++)
      #pragma unroll
      for (int r=0;r<4;r++)
        s[mt][r] += __shfl_xor(s[mt][r], off);
  if (ln == 0){
    float add = (blockIdx.x == 0 && wn == 0) ? vob[0] : 0.f;
    #pragma unroll
    for (int mt=0;mt<4;mt++)
      #pragma unroll
      for (int r=0;r<4;r++)
        atomicAdd(&values[m0 + wm*64 + mt*16 + quad*4 + r], s[mt][r] + add);
  }
}

// ---------------------------------------------------------------------------
// MFMA GRU v8 (unchanged from round 12, 87 us): single-term fp16, 128 blocks
// x 4 rows, broadcast A-reads, in-wave gates, 1 barrier/step, reset-carry.
// ---------------------------------------------------------------------------
__global__ __launch_bounds__(512, 1)
void grum8_k(const ushort* __restrict__ gih, const float* __restrict__ hidden0,
             const int* __restrict__ dones, const float* __restrict__ gWh,
             const float* __restrict__ bhn, __hip_bfloat16* __restrict__ eb_out,
             float* __restrict__ hout)
{
  __shared__ ushort wstg[32*392];
  __shared__ ushort hb[2][16*136];
  __shared__ float  dnS[T_*4];
  const int tid  = threadIdx.x;
  const int lane = tid & 63, wave = tid >> 6;
  const int quad = lane >> 4, ln = lane & 15;
  const int r0   = blockIdx.x * 4;
  const int col  = wave*16 + ln;
  const int lnb  = ln & 12;

  dnS[tid] = (dones[(size_t)(tid>>2)*B_ + r0 + (tid&3)] != 0) ? 1.f : 0.f;
  const float bhnr = bhn[col];

  for (int i=tid; i<16*136; i+=512){ hb[0][i]=0; hb[1][i]=0; }

  f16x8 bf[3][4];
  #pragma unroll
  for (int kc=0; kc<4; kc++){
    for (int i=tid; i<32*384; i+=512){
      int kk = i/384, c = i - kk*384;
      wstg[kk*392 + c] = f2hu(gWh[(size_t)(kc*32+kk)*384 + c]);
    }
    __syncthreads();
    #pragma unroll
    for (int g=0; g<3; g++){
      int c = g*128 + col;
      ushort tmp[8];
      #pragma unroll
      for (int j=0;j<8;j++) tmp[j] = wstg[(quad*8+j)*392 + c];
      bf[g][kc] = *(const f16x8*)tmp;
    }
    __syncthreads();
  }

  float hc = hidden0[(size_t)(r0+quad)*D_ + col];
  if (dnS[quad] > 0.5f) hc = 0.f;
  hb[0][(quad*4)*136 + col] = f2hu(hc);
  __syncthreads();

  float c_r, c_z, c_n;
  {
    const ushort* gp = gih + ((size_t)(r0+quad))*384;
    c_r = hu2f(gp[col]); c_z = hu2f(gp[col+128]); c_n = hu2f(gp[col+256]);
  }

  ushort pend_eu = 0;

  for (int t=0; t<T_; t++){
    if (t > 0)
      ((ushort*)eb_out)[((size_t)(t-1)*B_ + r0+quad)*D_ + col] = pend_eu;

    float n_r=0.f, n_z=0.f, n_n=0.f;
    if (t+1 < T_){
      const ushort* gp = gih + ((size_t)(t+1)*B_ + r0+quad)*384;
      n_r = hu2f(gp[col]); n_z = hu2f(gp[col+128]); n_n = hu2f(gp[col+256]);
    }

    const ushort* hbuf = hb[t&1];
    f32x4 acc[3];
    #pragma unroll
    for (int g=0;g<3;g++)
      #pragma unroll
      for (int r=0;r<4;r++) acc[g][r]=0.f;
    #pragma unroll
    for (int ks=0; ks<4; ks++){
      f16x8 ah = *(const f16x8*)&hbuf[lnb*136 + ks*32 + quad*8];
      #pragma unroll
      for (int g=0;g<3;g++)
        acc[g] = __builtin_amdgcn_mfma_f32_16x16x32_f16(ah, bf[g][ks], acc[g], 0,0,0);
    }

    const float dnow  = dnS[t*4 + quad];
    const float dnext = (t+1 < T_) ? dnS[(t+1)*4 + quad] : 0.f;
    float rg = sigmoidf_(c_r + acc[0][0]);
    float zg = sigmoidf_(c_z + acc[1][0]);
    float x  = c_n + rg*(acc[2][0] + bhnr);
    float ng = 2.f/(1.f+__expf(-2.f*x)) - 1.f;
    float hnew = (1.f - zg)*ng + zg*hc;
    pend_eu = f2bu(hnew*(1.f-dnow));
    float hv = (dnext > 0.5f) ? 0.f : hnew;
    hc = hv;
    hb[(t+1)&1][(quad*4)*136 + col] = f2hu(hv);
    __syncthreads();
    c_r = n_r; c_z = n_z; c_n = n_n;
  }
  ((ushort*)eb_out)[((size_t)(T_-1)*B_ + r0+quad)*D_ + col] = pend_eu;
  hout[(size_t)(r0+quad)*D_ + col] = hc;
}

// ---------------------------------------------------------------------------
// Fused preamble (one dispatch).
// ---------------------------------------------------------------------------
__global__ __launch_bounds__(256)
void packall_k(const float* __restrict__ obs, ushort* __restrict__ obsH,
               const float* __restrict__ e1w, ushort* __restrict__ e1T,
               const float* __restrict__ e2w, ushort* __restrict__ e2T,
               const float* __restrict__ gWi, ushort* __restrict__ giT,
               const float* __restrict__ chw, __hip_bfloat16* __restrict__ bcatT,
               const float* __restrict__ uhw, __hip_bfloat16* __restrict__ uhwT,
               const float* __restrict__ uow, __hip_bfloat16* __restrict__ uowT,
               const float* __restrict__ v1w, __hip_bfloat16* __restrict__ v1wT,
               const float* __restrict__ v2w, __hip_bfloat16* __restrict__ v2wT)
{
  const int b = blockIdx.x, tid = threadIdx.x;
  if (b < 16384){
    int idx = b*256 + tid;
    obsH[idx] = f2hu(obs[idx]);
  } else if (b < 16416){
    int idx = (b-16384)*256 + tid;
    int n = idx >> 6, k = idx & 63;
    e1T[idx] = f2hu(e1w[k*128 + n]);
  } else if (b < 16480){
    int idx = (b-16416)*256 + tid;
    int n = idx >> 7, k = idx & 127;
    e2T[idx] = f2hu(e2w[k*128 + n]);
  } else if (b < 16672){
    int idx = (b-16480)*256 + tid;
    int n = idx >> 7, k = idx & 127;
    giT[idx] = f2hu(gWi[k*384 + n]);
  } else if (b < 16800){
    int idx = (b-16672)*256 + tid;
    int n = idx >> 7, k = idx & 127;
    float v = (n < 128) ? chw[k*128 + n] : chw[(128+k)*128 + (n-128)];
    bcatT[idx] = __float2bfloat16(v);
  } else if (b < 16928){
    int idx = (b-16800)*256 + tid;
    int r = idx >> 7, c = idx & 127;
    uhwT[c*256 + r] = __float2bfloat16(uhw[idx]);
  } else if (b < 16992){
    int idx = (b-16928)*256 + tid;
    int r = idx >> 7, c = idx & 127;
    uowT[c*128 + r] = __float2bfloat16(uow[idx]);
  } else if (b < 17120){
    int idx = (b-16992)*256 + tid;
    int r = idx >> 8, c = idx & 255;
    v1wT[c*128 + r] = __float2bfloat16(v1w[idx]);
  } else {
    int idx = (b-17120)*256 + tid;
    int r = idx >> 8, c = idx & 255;
    v2wT[c*256 + r] = __float2bfloat16(v2w[idx]);
  }
}

extern "C" void kernel_launch(void* const* d_in, const int* in_sizes, int n_in,
                              void* d_out, int out_size, void* d_ws, size_t ws_size,
                              hipStream_t stream) {
  const float* hidden = (const float*)d_in[0];
  const float* obs    = (const float*)d_in[1];
  const int*   dones  = (const int*)  d_in[2];
  const float* e1w = (const float*)d_in[3];
  const float* e1b = (const float*)d_in[4];
  const float* e2w = (const float*)d_in[5];
  const float* e2b = (const float*)d_in[6];
  const float* gWi = (const float*)d_in[7];
  const float* gbi = (const float*)d_in[8];
  const float* gWh = (const float*)d_in[9];
  const float* gbhn= (const float*)d_in[10];
  const float* chw = (const float*)d_in[11];
  const float* chb = (const float*)d_in[12];
  const float* cow = (const float*)d_in[13];
  const float* cob = (const float*)d_in[14];
  const float* uhw = (const float*)d_in[15];
  const float* uhb = (const float*)d_in[16];
  const float* uow = (const float*)d_in[17];
  const float* uob = (const float*)d_in[18];
  const float* v1w = (const float*)d_in[19];
  const float* v1b = (const float*)d_in[20];
  const float* v2w = (const float*)d_in[21];
  const float* v2b = (const float*)d_in[22];
  const float* vow = (const float*)d_in[23];
  const float* vob = (const float*)d_in[24];
  (void)in_sizes; (void)n_in; (void)out_size;

  float* out_hidden = (float*)d_out;
  float* out_values = (float*)d_out + (size_t)B_*D_;

  // Arena (float-slot offsets). Peak ~27.4M slots = 110 MB.
  float* ws = (float*)d_ws;
  ushort* obsH  = (ushort*)(ws);                      // [0, 2.10M)
  ushort* emb1H = (ushort*)(ws + 2097152);            // [2.10M, 6.29M)
  ushort* emb2H = (ushort*)(ws + 6291456);            // [6.29M, 10.49M)
  ushort* giH   = (ushort*)(ws + 10485760);           // [10.49M, 23.07M)
  __hip_bfloat16* Xe = (__hip_bfloat16*)(ws + 23068672); // [23.07M, 27.26M)
  ushort* wb    = (ushort*)(ws + 27262976);           // weights
  // post-GRU overlays (obs/emb/gi regions dead after grum):
  __hip_bfloat16* Xc    = (__hip_bfloat16*)(ws);              // [0, 4.19M)
  __hip_bfloat16* v1b16 = (__hip_bfloat16*)(ws + 4194304);    // [4.19M, 12.58M)
  if (ws_size < (size_t)27500000 * sizeof(float)) return;

  __hip_bfloat16* bcatT = (__hip_bfloat16*)wb;           // [256][128]
  __hip_bfloat16* uhwT  = (__hip_bfloat16*)wb + 32768;   // [128][256]
  __hip_bfloat16* uowT  = (__hip_bfloat16*)wb + 65536;   // [128][128]
  __hip_bfloat16* v1wT  = (__hip_bfloat16*)wb + 81920;   // [256][128]
  __hip_bfloat16* v2wT  = (__hip_bfloat16*)wb + 114688;  // [256][256]
  ushort* e1wT = wb + 180224;   // [128][64]  fp16
  ushort* e2wT = wb + 188416;   // [128][128] fp16
  ushort* gWiT = wb + 204800;   // [384][128] fp16

  dim3 blk(256);
  hipMemsetAsync(out_values, 0, (size_t)M_*sizeof(float), stream);
  packall_k<<<dim3(17376), blk, 0, stream>>>(
    obs, obsH, e1w, e1wT, e2w, e2wT, gWi, gWiT,
    chw, bcatT, uhw, uhwT, uow, uowT, v1w, v1wT, v2w, v2wT);

  // embeds + gi: single-term fp16 MFMA
  mgemmh_k<1><<<dim3(2,512), blk, 0, stream>>>(obsH,  e1wT, e1b, emb1H, M_, 128, 64);
  mgemmh_k<1><<<dim3(2,512), blk, 0, stream>>>(emb1H, e2wT, e2b, emb2H, M_, 128, 128);
  mgemmh_k<0><<<dim3(6,512), blk, 0, stream>>>(emb2H, gWiT, gbi, giH,   M_, 384, 128);

  // MFMA GRU
  grum8_k<<<dim3(128), dim3(512), 0, stream>>>(giH, hidden, dones, gWh, gbhn, Xe, out_hidden);

  for (int it=0; it<2; it++){
    couple2_k<<<dim3(T_*NE_), blk, 0, stream>>>(Xe, (const ushort*)bcatT, chb, cow, cob, Xc);
    updf_k<<<dim3(512), blk, 0, stream>>>(Xe, Xc, uhwT, uhb, uowT, uob, dones, Xe);
  }
  // value head: v1 GEMM, then fused v2+dot
  mgemm_k<1><<<dim3(2,512), blk, 0, stream>>>(Xe, v1wT, v1b, v1b16, M_, 256, 128);
  vhead2_k<<<dim3(2,512), blk, 0, stream>>>(v1b16, v2wT, v2b, vow, vob, out_values);
}